// Round 20
// baseline (570.467 us; speedup 1.0000x reference)
//
#include <hip/hip_runtime.h>
#include <stdint.h>

#define N_IMGS 8
#define NLVL 5
#define TOT 392832          // total anchors across levels
#define PRE_K 1000
#define POST_K 1000
#define KSEL 5000           // 5 levels * 1000
#define MASKW 79            // ceil(5000/64)
#define MROWS 5056          // KSEL padded to 79 full 64-row chunks
#define NCHUNK 79
#define LPAD 1024           // per-level padded list length
#define MSLOTS (NLVL * LPAD)
#define HCOPY 4100          // 4096 bins + 4 pad
#define CANDMAX 4096
#define SLICE 16384         // elements per hist/compact slice
#define NSLICE 27           // slices per image: 18+5+2+1+1
#define NWS (N_IMGS * NSLICE * 4)   // wave-slots for counting
#define GH_U32 (N_IMGS * NLVL * 4096)
#define SLOTROWS 16

typedef unsigned long long u64;

struct Ptrs {
    const float* obj[5];
    const float* del[5];
    const float* anch;
};

__device__ __forceinline__ unsigned flipb(unsigned u) {
    return (u & 0x80000000u) ? ~u : (u | 0x80000000u);
}

__device__ __forceinline__ void lvl_info(int t, int& l, int& off, int& W, int& H) {
    if (t < 294912)      { l = 0; off = 0;      W = 384; H = 256; }
    else if (t < 368640) { l = 1; off = 294912; W = 192; H = 128; }
    else if (t < 387072) { l = 2; off = 368640; W = 96;  H = 64;  }
    else if (t < 391680) { l = 3; off = 387072; W = 48;  H = 32;  }
    else                 { l = 4; off = 391680; W = 24;  H = 16;  }
}

__device__ __forceinline__ void slice_info(int s, int& l, int& sl) {
    if (s < 18)      { l = 0; sl = s; }
    else if (s < 23) { l = 1; sl = s - 18; }
    else if (s < 25) { l = 2; sl = s - 23; }
    else if (s < 26) { l = 3; sl = s - 25; }
    else             { l = 4; sl = s - 26; }
}

__device__ __forceinline__ void lvl_consts(int l, int& len, int& off, int& HW) {
    switch (l) {
    case 0: len = 294912; off = 0;      HW = 98304; break;
    case 1: len = 73728;  off = 294912; HW = 24576; break;
    case 2: len = 18432;  off = 368640; HW = 6144;  break;
    case 3: len = 4608;   off = 387072; HW = 1536;  break;
    default: len = 1152;  off = 391680; HW = 384;   break;
    }
}

__device__ __forceinline__ void lvl_slices(int l, int& sbase, int& nsl) {
    switch (l) {
    case 0: sbase = 0;  nsl = 18; break;
    case 1: sbase = 18; nsl = 5;  break;
    case 2: sbase = 23; nsl = 2;  break;
    case 3: sbase = 25; nsl = 1;  break;
    default: sbase = 26; nsl = 1; break;
    }
}

// Decode one proposal exactly as the reference (f32, no FMA contraction).
__device__ void decode_one(const Ptrs& P, int n, int t, float bx[4], bool& valid, int& lvl) {
#pragma clang fp contract(off)
    int l, off, W, H;
    lvl_info(t, l, off, W, H);
    lvl = l;
    int i = t - off;
    int a = i % 3;
    int p = i / 3;
    int y = p / W, x = p - y * W;
    const float* D = P.del[l];
    size_t plane = (size_t)W * H;
    size_t base = ((size_t)n * 12 + (size_t)a * 4) * plane + (size_t)y * W + x;
    float dx = D[base];
    float dy = D[base + plane];
    float dw = D[base + 2 * plane];
    float dh = D[base + 3 * plane];
    const float* an = P.anch + (size_t)t * 4;
    float a0 = an[0], a1 = an[1], a2 = an[2], a3 = an[3];
    float wa = a2 - a0, ha = a3 - a1;
    float cxa = a0 + 0.5f * wa, cya = a1 + 0.5f * ha;
    const float CLIP = 4.135166556742356f;  // log(1000/16) rounded to f32
    dw = fminf(dw, CLIP);
    dh = fminf(dh, CLIP);
    float cx = dx * wa + cxa;
    float cy = dy * ha + cya;
    float pw = expf(dw) * wa;
    float ph = expf(dh) * ha;
    float x1 = cx - 0.5f * pw, y1 = cy - 0.5f * ph;
    float x2 = cx + 0.5f * pw, y2 = cy + 0.5f * ph;
    x1 = fminf(fmaxf(x1, 0.f), 1536.f);
    x2 = fminf(fmaxf(x2, 0.f), 1536.f);
    y1 = fminf(fmaxf(y1, 0.f), 1024.f);
    y2 = fminf(fmaxf(y2, 0.f), 1024.f);
    bx[0] = x1; bx[1] = y1; bx[2] = x2; bx[3] = y2;
    valid = ((x2 - x1) >= 1e-3f) && ((y2 - y1) >= 1e-3f);
}

__global__ void k_zero_out(float* out, int n) {
    int i = blockIdx.x * blockDim.x + threadIdx.x;
    if (i < n) out[i] = 0.f;
}

__global__ void k_zero32(unsigned* p, int n) {
    int i = blockIdx.x * blockDim.x + threadIdx.x;
    if (i < n) p[i] = 0u;
}

// Per-slice 12-bit histogram straight from obj tensors.
__global__ __launch_bounds__(256) void k_hist(Ptrs P, unsigned* ghist) {
    int img = blockIdx.x / NSLICE, s = blockIdx.x % NSLICE;
    int l, sl; slice_info(s, l, sl);
    int len, off, HW; lvl_consts(l, len, off, HW);
    int start = sl * SLICE;
    int cnt4 = min(SLICE, len - start) >> 2;
    const uint4* S4 = (const uint4*)(P.obj[l] + (size_t)img * 3 * HW + start);
    __shared__ unsigned hist[2 * HCOPY];
    int t = threadIdx.x;
    for (int i = t; i < 2 * HCOPY; i += 256) hist[i] = 0u;
    __syncthreads();
    unsigned* myh = hist + (t & 1) * HCOPY;
    for (int i = t; i < cnt4; i += 256) {
        uint4 v = S4[i];
        atomicAdd(&myh[flipb(v.x) >> 20], 1u);
        atomicAdd(&myh[flipb(v.y) >> 20], 1u);
        atomicAdd(&myh[flipb(v.z) >> 20], 1u);
        atomicAdd(&myh[flipb(v.w) >> 20], 1u);
    }
    __syncthreads();
    unsigned* G = ghist + (size_t)(img * 5 + l) * 4096;
    for (int b = t; b < 4096; b += 256) {
        unsigned v = hist[b] + hist[HCOPY + b];
        if (v) atomicAdd(&G[b], v);
    }
}

// Per-task pivot find (suffix scan over the 4096-bin global histogram).
__global__ __launch_bounds__(1024) void k_pivot(const unsigned* ghist, uint2* pivinfo,
                                                int* vcnt) {
    int task = blockIdx.x;
    int t = threadIdx.x;
    if (task == 0 && t < N_IMGS) vcnt[t] = KSEL;
    __shared__ unsigned hl[4096];
    __shared__ unsigned suf[1024];
    const unsigned* H = ghist + (size_t)task * 4096;
    for (int i = t; i < 4096; i += 1024) hl[i] = H[i];
    __syncthreads();
    suf[t] = hl[4 * t] + hl[4 * t + 1] + hl[4 * t + 2] + hl[4 * t + 3];
    for (int d = 1; d < 1024; d <<= 1) {
        __syncthreads();
        unsigned v = (t + d < 1024) ? suf[t + d] : 0u;
        __syncthreads();
        suf[t] += v;
    }
    __syncthreads();
    unsigned above = (t == 1023) ? 0u : suf[t + 1];
    if (suf[t] >= PRE_K && above < PRE_K) {
        int b = 4 * t + 3;
        unsigned c = above;
        while (c + hl[b] < PRE_K) { c += hl[b]; --b; }
        pivinfo[task] = make_uint2((unsigned)b, PRE_K - c);
    }
}

// Phase A: per-wave hit counts, register-only in the loop.
__global__ __launch_bounds__(256) void k_cnt(Ptrs P, const uint2* pivinfo,
                                             unsigned* cntgt, unsigned* cnteq) {
    int img = blockIdx.x / NSLICE, s = blockIdx.x % NSLICE;
    int l, sl; slice_info(s, l, sl);
    int len, off, HW; lvl_consts(l, len, off, HW);
    int start = sl * SLICE;
    int cnt4 = min(SLICE, len - start) >> 2;
    int task = img * 5 + l;
    unsigned pivot = pivinfo[task].x;
    const uint4* S4 = (const uint4*)(P.obj[l] + (size_t)img * 3 * HW + start);
    int t = threadIdx.x, lane = t & 63, wv = t >> 6;
    unsigned cg = 0u, ce = 0u;
    for (int i = t; i < cnt4; i += 256) {
        uint4 v = S4[i];
        unsigned vv[4] = {v.x, v.y, v.z, v.w};
#pragma unroll
        for (int q = 0; q < 4; ++q) {
            unsigned b = flipb(vv[q]) >> 20;
            cg += (b > pivot);
            ce += (b == pivot);
        }
    }
    for (int d = 1; d < 64; d <<= 1) {
        cg += (unsigned)__shfl_xor((int)cg, d, 64);
        ce += (unsigned)__shfl_xor((int)ce, d, 64);
    }
    if (lane == 0) {
        int ws = blockIdx.x * 4 + wv;
        cntgt[ws] = cg;
        cnteq[ws] = ce;
    }
}

// Phase B: per-task exclusive scan of wave counts -> base offsets; nc = eq total.
__global__ __launch_bounds__(128) void k_off(const unsigned* cntgt, const unsigned* cnteq,
                                             unsigned* basegt, unsigned* baseeq, int* nc) {
    int task = blockIdx.x;
    int img = task / 5, l = task % 5;
    int sbase, nsl; lvl_slices(l, sbase, nsl);
    int nws = nsl * 4;
    int wsbase = (img * NSLICE + sbase) * 4;
    __shared__ unsigned sg[128], se[128];
    int t = threadIdx.x;
    unsigned g0 = (t < nws) ? cntgt[wsbase + t] : 0u;
    unsigned e0 = (t < nws) ? cnteq[wsbase + t] : 0u;
    sg[t] = g0; se[t] = e0;
    for (int d = 1; d < 128; d <<= 1) {
        __syncthreads();
        unsigned ag = (t >= d) ? sg[t - d] : 0u;
        unsigned ae = (t >= d) ? se[t - d] : 0u;
        __syncthreads();
        sg[t] += ag; se[t] += ae;
    }
    __syncthreads();
    if (t < nws) {
        basegt[wsbase + t] = sg[t] - g0;   // exclusive prefix
        baseeq[wsbase + t] = se[t] - e0;
    }
    if (t == 0) nc[task] = (int)se[127];   // total eq (pads contribute 0)
}

// Phase C: re-read, ballot-prefix slot assignment (no atomics).
__global__ __launch_bounds__(256) void k_write(Ptrs P, const uint2* pivinfo,
                                               const unsigned* basegt, const unsigned* baseeq,
                                               uint2* sel, u64* cand) {
    int img = blockIdx.x / NSLICE, s = blockIdx.x % NSLICE;
    int l, sl; slice_info(s, l, sl);
    int len, off, HW; lvl_consts(l, len, off, HW);
    int start = sl * SLICE;
    int cnt4 = min(SLICE, len - start) >> 2;
    int task = img * 5 + l;
    unsigned pivot = pivinfo[task].x;
    const uint4* S4 = (const uint4*)(P.obj[l] + (size_t)img * 3 * HW + start);
    uint2* out = sel + (size_t)task * PRE_K;
    u64* cd = cand + (size_t)task * CANDMAX;
    int t = threadIdx.x, lane = t & 63, wv = t >> 6;
    int ws = blockIdx.x * 4 + wv;
    unsigned og = basegt[ws], oe = baseeq[ws];
    u64 below = (1ull << lane) - 1ull;
    int iters = (cnt4 + 255) >> 8;
    uint4 nxt = (t < cnt4) ? S4[t] : make_uint4(0u, 0u, 0u, 0u);
    for (int it = 0; it < iters; ++it) {
        int ii = it * 256 + t;
        bool live = ii < cnt4;
        uint4 cur = nxt;
        int jj = (it + 1) * 256 + t;
        if (it + 1 < iters) nxt = (jj < cnt4) ? S4[jj] : make_uint4(0u, 0u, 0u, 0u);
        unsigned vv[4] = {cur.x, cur.y, cur.z, cur.w};
#pragma unroll
        for (int q = 0; q < 4; ++q) {
            unsigned u = flipb(vv[q]);
            unsigned b = u >> 20;
            bool gt = live && (b > pivot);
            bool eq = live && (b == pivot);
            unsigned tf = 0u;
            if (gt || eq) {
                int i = start + 4 * ii + q;
                int a = i / HW, rem = i - a * HW;
                tf = (unsigned)(off + rem * 3 + a);
            }
            u64 mg = __ballot((int)gt);
            if (gt) out[og + (unsigned)__popcll(mg & below)] = make_uint2(u, tf);
            og += (unsigned)__popcll(mg);
            u64 me = __ballot((int)eq);
            if (eq) {
                unsigned slot = oe + (unsigned)__popcll(me & below);
                if (slot < CANDMAX) cd[slot] = ((u64)u << 32) | (u64)tf;
            }
            oe += (unsigned)__popcll(me);
        }
    }
}

// Exact rank among pivot-bin candidates (lax.top_k tie semantics).
__global__ __launch_bounds__(1024) void k_rank(const uint2* pivinfo, const u64* cand,
                                               const int* nc, uint2* sel) {
    int task = blockIdx.x;
    int t = threadIdx.x;
    int C = min(nc[task], CANDMAX);
    int krem = (int)pivinfo[task].y;
    int nbase = PRE_K - krem;
    __shared__ u64 lc[CANDMAX];
    const u64* cd = cand + (size_t)task * CANDMAX;
    for (int i = t; i < C; i += 1024) lc[i] = cd[i];
    __syncthreads();
    uint2* out = sel + (size_t)task * PRE_K;
    for (int i = t; i < C; i += 1024) {
        u64 a = lc[i];
        unsigned vi = (unsigned)(a >> 32), xi = (unsigned)a;
        int rank = 0;
        for (int j = 0; j < C; ++j) {
            u64 bj = lc[j];
            unsigned vj = (unsigned)(bj >> 32), xj = (unsigned)bj;
            rank += (vj > vi) || (vj == vi && xj < xi);
        }
        if (rank < krem) out[nbase + rank] = make_uint2(vi, xi);
    }
}

// Fused key-build + per-(image,level) bitonic sort of 1024-padded list.
__global__ __launch_bounds__(1024) void k_sort1(Ptrs P, const uint2* sel, u64* keys2) {
    __shared__ u64 s[LPAD];
    int task = blockIdx.x;          // n*5 + l
    int n = task / 5;
    int t = threadIdx.x;
    u64 key = ~0ull;
    if (t < PRE_K) {
        uint2 sv = sel[(size_t)task * PRE_K + t];
        float bx[4]; bool valid; int lv;
        decode_one(P, n, (int)sv.y, bx, valid, lv);
        key = valid ? (((u64)(~sv.x) << 32) | (u64)sv.y)
                    : (0xFFFFFFFF00000000ull | (u64)sv.y);
    }
    s[t] = key;
    for (int k = 2; k <= LPAD; k <<= 1) {
        for (int j = k >> 1; j > 0; j >>= 1) {
            __syncthreads();
            int ixj = t ^ j;
            if (ixj > t) {
                u64 a = s[t], b = s[ixj];
                bool asc = ((t & k) == 0);
                if (asc ? (a > b) : (a < b)) { s[t] = b; s[ixj] = a; }
            }
        }
    }
    __syncthreads();
    keys2[(size_t)task * LPAD + t] = s[t];
}

// Fused stable 5-way merge-by-rank + decode + scatter.
__global__ void k_mergedec(Ptrs P, const u64* keys2,
                           float4* boxes, float4* nboxes, int* vcnt) {
    int idx = blockIdx.x * blockDim.x + threadIdx.x;
    if (idx >= N_IMGS * MSLOTS) return;
    int n = idx / MSLOTS, slot = idx - n * MSLOTS;
    int l = slot >> 10, p = slot & (LPAD - 1);
    const u64* base = keys2 + (size_t)n * MSLOTS;
    u64 key = base[(size_t)l * LPAD + p];
    if (key == ~0ull) return;       // pad slot
    int rank = p;
#pragma unroll
    for (int m = 0; m < NLVL; ++m) {
        if (m == l) continue;
        const u64* L = base + (size_t)m * LPAD;
        bool le = (m < l);
        int lo = 0, hi = LPAD;
        while (lo < hi) {
            int mid = (lo + hi) >> 1;
            u64 v = L[mid];
            bool take = le ? (v <= key) : (v < key);
            if (take) lo = mid + 1; else hi = mid;
        }
        rank += lo;
    }
    if (rank >= KSEL) return;
    int oidx = n * KSEL + rank;
    if ((key >> 32) == 0xFFFFFFFFull) {
        boxes[oidx] = make_float4(0.f, 0.f, 0.f, 0.f);
        nboxes[oidx] = make_float4(0.f, 0.f, 0.f, 0.f);
        atomicMin(&vcnt[n], rank);
        return;
    }
    int t = (int)(key & 0xFFFFFFFFull);
    float bx[4]; bool valid; int lv;
    decode_one(P, n, t, bx, valid, lv);
    boxes[oidx] = make_float4(bx[0], bx[1], bx[2], bx[3]);
    float offv = (float)lv * 1537.0f;   // (max(H,W)+1) * level
    nboxes[oidx] = make_float4(bx[0] + offv, bx[1] + offv, bx[2] + offv, bx[3] + offv);
}

// Suppression bitmask, ballot form, 2 col-blocks per wave. ROW-MAJOR output:
// mask[(n*MROWS + r)*MASKW + cb]. Only upper blocks (cb >= rb) written; the
// lower-tri words stay garbage — k_scan folds a row's words only after that
// row's chunk has been consumed, so garbage words never affect a live read.
__device__ __forceinline__ float rdlane(float v, int src) {
    return __int_as_float(__builtin_amdgcn_readlane(__float_as_int(v), src));
}
__global__ __launch_bounds__(64) void k_mask(const float4* __restrict__ nboxes,
                                             u64* __restrict__ mask) {
#pragma clang fp contract(off)
    int rb = blockIdx.x, cs = blockIdx.y, n = blockIdx.z;
    int cb0 = cs * 2, cb1 = cb0 + 1;
    if (cb1 < rb) return;           // whole superblock below diagonal
    int lane = threadIdx.x;
    int r0 = rb * 64;
    const float4 z4 = make_float4(0.f, 0.f, 0.f, 0.f);
    const float4* B = nboxes + (size_t)n * KSEL;
    float4 rbx = (r0 + lane < KSEL) ? B[r0 + lane] : z4;
    float areaR = (rbx.z - rbx.x) * (rbx.w - rbx.y);
    float4 cA = (cb0 * 64 + lane < KSEL) ? B[cb0 * 64 + lane] : z4;
    float4 cB = (cb1 * 64 + lane < KSEL && cb1 < MASKW) ? B[cb1 * 64 + lane] : z4;
    float aCA = (cA.z - cA.x) * (cA.w - cA.y);
    float aCB = (cB.z - cB.x) * (cB.w - cB.y);
    u64 cmA = __ballot(cb0 * 64 + lane < KSEL);
    u64 cmB = __ballot(cb1 * 64 + lane < KSEL && cb1 < MASKW);
    const double MID = 0x1.666667p-1;
    u64 wA = 0ull, wB = 0ull;
#pragma unroll 4
    for (int rr = 0; rr < 64; ++rr) {
        float rx1 = rdlane(rbx.x, rr), ry1 = rdlane(rbx.y, rr);
        float rx2 = rdlane(rbx.z, rr), ry2 = rdlane(rbx.w, rr);
        float aR  = rdlane(areaR, rr);
        float wvA = fmaxf(fminf(rx2, cA.z) - fmaxf(rx1, cA.x), 0.f);
        float hvA = fmaxf(fminf(ry2, cA.w) - fmaxf(ry1, cA.y), 0.f);
        float inA = wvA * hvA;
        float unA = (aR + aCA) - inA;
        bool supA = (double)inA >= MID * (double)unA;
        float wvB = fmaxf(fminf(rx2, cB.z) - fmaxf(rx1, cB.x), 0.f);
        float hvB = fmaxf(fminf(ry2, cB.w) - fmaxf(ry1, cB.y), 0.f);
        float inB = wvB * hvB;
        float unB = (aR + aCB) - inB;
        bool supB = (double)inB >= MID * (double)unB;
        u64 a = __ballot((int)supA) & cmA;
        u64 b = __ballot((int)supB) & cmB;
        u64 dm = ~((2ull << rr) - 1ull);
        if (rb == cb0) a &= dm;
        if (rb == cb1) b &= dm;
        wA = (lane == rr) ? a : wA;
        wB = (lane == rr) ? b : wB;
    }
    if (r0 + lane < KSEL) {
        size_t row = ((size_t)n * MROWS + r0 + lane) * MASKW;
        if (cb0 >= rb) mask[row + cb0] = wA;
        if (cb1 < MASKW) mask[row + cb1] = wB;
    }
}

__device__ __forceinline__ u64 bcast64(u64 v, int src) {
    unsigned lo = (unsigned)__builtin_amdgcn_readlane((int)(unsigned)v, src);
    unsigned hi = (unsigned)__builtin_amdgcn_readlane((int)(unsigned)(v >> 32), src);
    return ((u64)hi << 32) | (u64)lo;
}

// Wave64 OR-reduce via DPP, result in lane 63.
__device__ __forceinline__ unsigned or_red_dpp(unsigned v) {
    v |= (unsigned)__builtin_amdgcn_update_dpp(0, (int)v, 0x111, 0xf, 0xf, true);
    v |= (unsigned)__builtin_amdgcn_update_dpp(0, (int)v, 0x112, 0xf, 0xf, true);
    v |= (unsigned)__builtin_amdgcn_update_dpp(0, (int)v, 0x114, 0xf, 0xf, true);
    v |= (unsigned)__builtin_amdgcn_update_dpp(0, (int)v, 0x118, 0xf, 0xf, true);
    v |= (unsigned)__builtin_amdgcn_update_dpp(0, (int)v, 0x142, 0xa, 0xf, false);
    v |= (unsigned)__builtin_amdgcn_update_dpp(0, (int)v, 0x143, 0xc, 0xf, false);
    return v;
}

// Single-wave greedy NMS scan, incremental rem + slot-deferred global_load_lds:
//  - rem distributed (lane L owns words L, 64+L); each kept row's full 632B is
//    read ONCE: issued as exactly 16 global_load_lds at end of its chunk
//    (dummies -> trash slot keep vmcnt accounting constant, zero result VGPRs),
//    folded from LDS into rem at the top of chunk c+2 behind a counted
//    s_waitcnt vmcnt(18) (= the 2 prefetches + 16 row loads issued since);
//  - chunk c-1's keeps covered by the address-independent nc-column DPP trick;
//  - chunk c's own keeps by the in-chain wc broadcast;
//  - overflow (>16 keeps/chunk, rare) folds directly with immediate loads;
//  - keeps buffered in LDS so no stores pollute the vmcnt stream.
__global__ __launch_bounds__(64, 1) void k_scan(const u64* mask, const int* vcnt,
                                                int* keep, int* nkept) {
    __shared__ __align__(16) u64 rowbuf[2][SLOTROWS][80];
    __shared__ __align__(16) u64 trash[80];
    __shared__ int keep_lds[POST_K];
    int n = blockIdx.x, lane = threadIdx.x;
    int V = vcnt[n];
    const u64* M = mask + (size_t)n * MROWS * MASKW;
    int nchunks = (V + 63) >> 6;

    u64 rem_lo = 0ull, rem_hi = 0ull;
    u64 keptprev = 0ull;
    int kslot[2] = {0, 0};      // real rows in each slot (wave-uniform)
    int cnt = 0;
    bool full = false;
    int hiw = 64 + (int)lane; if (hiw > 79) hiw = 79;   // in-bounds LDS idx

    u64 wc = M[(size_t)lane * MASKW];   // word 0 of rows 0..63
    u64 nc = 0ull;

    for (int c = 0; c < nchunks && !full; ++c) {
        int slot = c & 1;
        // ---- fold chunk c-2's kept rows from LDS (loads issued 2 chunks ago) ----
        int kf = kslot[slot];
        if (kf > 0) {
            asm volatile("s_waitcnt vmcnt(18)" ::: "memory");
#pragma unroll
            for (int q = 0; q < SLOTROWS; ++q) {
                u64 a = rowbuf[slot][q][lane];
                u64 b = rowbuf[slot][q][hiw];
                rem_lo |= (q < kf) ? a : 0ull;
                rem_hi |= (q < kf && lane < 15) ? b : 0ull;
            }
        }

        // ---- suppression word for chunk c ----
        u64 cur = bcast64((c < 64) ? rem_lo : rem_hi, c & 63);
        {
            u64 part = ((keptprev >> lane) & 1ull) ? nc : 0ull;
            unsigned plo = or_red_dpp((unsigned)part);
            unsigned phi = or_red_dpp((unsigned)(part >> 32));
            cur |= ((u64)(unsigned)__builtin_amdgcn_readlane((int)phi, 63) << 32)
                 | (u64)(unsigned)__builtin_amdgcn_readlane((int)plo, 63);
        }

        // ---- prefetch next chunk's nc / wc (address-independent) ----
        int colN = (c + 1 < NCHUNK) ? (c + 1) : (NCHUNK - 1);
        u64 nc_next = M[((size_t)c * 64 + lane) * MASKW + colN];
        u64 wc_next = M[((size_t)colN * 64 + lane) * MASKW + colN];

        // ---- serial chain (wave-uniform) ----
        int base = c * 64;
        int jmax = V - base; if (jmax > 64) jmax = 64;
        u64 avail = ~cur;
        if (jmax < 64) avail &= (1ull << jmax) - 1ull;
        u64 keptbits = 0ull;
        while (avail) {
            int j = __builtin_ctzll(avail);
            if (lane == 0) keep_lds[cnt] = base + j;
            ++cnt;
            keptbits |= 1ull << j;
            if (cnt == POST_K) { full = true; break; }
            u64 wcj = bcast64(wc, j);
            avail &= avail - 1;
            avail &= ~wcj;
        }

        // ---- issue exactly 16 global_load_lds for this chunk's keeps ----
        {
            u64 kb = keptbits;
            int nk = 0;
#pragma unroll
            for (int q = 0; q < SLOTROWS; ++q) {
                bool real = (kb != 0ull);
                int r = 0;
                if (real) { r = base + (int)__builtin_ctzll(kb); kb &= kb - 1; ++nk; }
                const char* src = (const char*)(M + (size_t)r * MASKW);
                char* dst = (char*)(real ? &rowbuf[slot][q][0] : &trash[0]);
                if (lane < 40)
                    __builtin_amdgcn_global_load_lds(
                        (const __attribute__((address_space(1))) unsigned int*)(src + (size_t)lane * 16),
                        (__attribute__((address_space(3))) unsigned int*)dst, 16, 0, 0);
            }
            kslot[slot] = nk;
            // overflow: fold immediately (rare, early chunks)
            while (kb) {
                int r = base + (int)__builtin_ctzll(kb);
                kb &= kb - 1;
                const u64* row = M + (size_t)r * MASKW;
                rem_lo |= row[lane];
                if (lane < 15) rem_hi |= row[64 + lane];
            }
        }

        keptprev = keptbits;
        wc = wc_next;
        nc = nc_next;
    }

    for (int i = lane; i < cnt; i += 64) keep[n * POST_K + i] = keep_lds[i];
    if (lane == 0) nkept[n] = cnt;
}

__global__ void k_out(const float4* boxes, const int* keep, const int* nkept, float4* out) {
    int idx = blockIdx.x * blockDim.x + threadIdx.x;
    if (idx >= N_IMGS * POST_K) return;
    int n = idx / POST_K, k = idx - n * POST_K;
    float4 v = make_float4(0.f, 0.f, 0.f, 0.f);
    if (k < nkept[n]) v = boxes[(size_t)n * KSEL + keep[n * POST_K + k]];
    out[idx] = v;
}

extern "C" void kernel_launch(void* const* d_in, const int* in_sizes, int n_in,
                              void* d_out, int out_size, void* d_ws, size_t ws_size,
                              hipStream_t stream) {
    // dict order: obj0, delta0, obj1, delta1, ..., obj4, delta4, anchors
    Ptrs P;
    for (int l = 0; l < 5; ++l) {
        P.obj[l] = (const float*)d_in[2 * l];
        P.del[l] = (const float*)d_in[2 * l + 1];
    }
    P.anch = (const float*)d_in[10];

    // workspace carve
    size_t o = 0;
    auto alloc = [&](size_t bytes) {
        size_t cur = o;
        o = (o + bytes + 255) & ~(size_t)255;
        return cur;
    };
    size_t off_gh     = alloc((size_t)GH_U32 * 4);
    size_t off_cnt    = alloc((size_t)NWS * 4 * 4);   // cntgt, cnteq, basegt, baseeq
    size_t off_nc     = alloc(64 * 4);
    size_t off_piv    = alloc((size_t)N_IMGS * NLVL * 8);
    size_t off_cand   = alloc((size_t)N_IMGS * NLVL * CANDMAX * 8);
    size_t off_sel    = alloc((size_t)N_IMGS * KSEL * 8);
    size_t off_keys2  = alloc((size_t)N_IMGS * MSLOTS * 8);
    size_t off_boxes  = alloc((size_t)N_IMGS * KSEL * 16);
    size_t off_nbox   = alloc((size_t)N_IMGS * KSEL * 16);
    size_t off_mask   = alloc((size_t)N_IMGS * MROWS * MASKW * 8 + 1024);  // +pad for 640B row overread
    size_t off_vcnt   = alloc(N_IMGS * 4);
    size_t off_keep   = alloc((size_t)N_IMGS * POST_K * 4);
    size_t off_nkept  = alloc(N_IMGS * 4);

    float* out = (float*)d_out;
    if (o > ws_size) {  // workspace too small: emit zeros (visible failure, no crash)
        k_zero_out<<<(out_size + 255) / 256, 256, 0, stream>>>(out, out_size);
        return;
    }

    char* w = (char*)d_ws;
    unsigned* ghist  = (unsigned*)(w + off_gh);
    unsigned* cntgt  = (unsigned*)(w + off_cnt);
    unsigned* cnteq  = cntgt + NWS;
    unsigned* basegt = cntgt + 2 * NWS;
    unsigned* baseeq = cntgt + 3 * NWS;
    int* nc          = (int*)(w + off_nc);
    uint2* pivinfo   = (uint2*)(w + off_piv);
    u64* cand        = (u64*)(w + off_cand);
    uint2* sel       = (uint2*)(w + off_sel);
    u64* keys2       = (u64*)(w + off_keys2);
    float4* boxes    = (float4*)(w + off_boxes);
    float4* nboxes   = (float4*)(w + off_nbox);
    u64* mask        = (u64*)(w + off_mask);
    int* vcnt        = (int*)(w + off_vcnt);
    int* keep        = (int*)(w + off_keep);
    int* nkept       = (int*)(w + off_nkept);

    k_zero32<<<(GH_U32 + 255) / 256, 256, 0, stream>>>(ghist, GH_U32);
    k_hist<<<N_IMGS * NSLICE, 256, 0, stream>>>(P, ghist);
    k_pivot<<<N_IMGS * NLVL, 1024, 0, stream>>>(ghist, pivinfo, vcnt);
    k_cnt<<<N_IMGS * NSLICE, 256, 0, stream>>>(P, pivinfo, cntgt, cnteq);
    k_off<<<N_IMGS * NLVL, 128, 0, stream>>>(cntgt, cnteq, basegt, baseeq, nc);
    k_write<<<N_IMGS * NSLICE, 256, 0, stream>>>(P, pivinfo, basegt, baseeq, sel, cand);
    k_rank<<<N_IMGS * NLVL, 1024, 0, stream>>>(pivinfo, cand, nc, sel);
    k_sort1<<<N_IMGS * NLVL, 1024, 0, stream>>>(P, sel, keys2);
    k_mergedec<<<(N_IMGS * MSLOTS + 255) / 256, 256, 0, stream>>>(P, keys2, boxes, nboxes, vcnt);
    k_mask<<<dim3(NCHUNK, (MASKW + 1) / 2, N_IMGS), 64, 0, stream>>>(nboxes, mask);
    k_scan<<<N_IMGS, 64, 0, stream>>>(mask, vcnt, keep, nkept);
    k_out<<<(N_IMGS * POST_K + 255) / 256, 256, 0, stream>>>((const float4*)boxes, keep, nkept, (float4*)d_out);
}

// Round 21
// 297.732 us; speedup vs baseline: 1.9160x; 1.9160x over previous
//
#include <hip/hip_runtime.h>
#include <stdint.h>

#define N_IMGS 8
#define NLVL 5
#define TOT 392832          // total anchors across levels
#define PRE_K 1000
#define POST_K 1000
#define KSEL 5000           // 5 levels * 1000
#define MASKW 79            // ceil(5000/64)
#define MROWS 5056          // KSEL padded to 79 full 64-row chunks
#define NCHUNK 79
#define LPAD 1024           // per-level padded list length
#define MSLOTS (NLVL * LPAD)
#define HCOPY 4100          // 4096 bins + 4 pad
#define CANDMAX 4096
#define SLICE 16384         // elements per hist/compact slice
#define NSLICE 27           // slices per image: 18+5+2+1+1
#define NWS (N_IMGS * NSLICE * 4)   // wave-slots for counting
#define GH_U32 (N_IMGS * NLVL * 4096)

typedef unsigned long long u64;

struct Ptrs {
    const float* obj[5];
    const float* del[5];
    const float* anch;
};

__device__ __forceinline__ unsigned flipb(unsigned u) {
    return (u & 0x80000000u) ? ~u : (u | 0x80000000u);
}

__device__ __forceinline__ void lvl_info(int t, int& l, int& off, int& W, int& H) {
    if (t < 294912)      { l = 0; off = 0;      W = 384; H = 256; }
    else if (t < 368640) { l = 1; off = 294912; W = 192; H = 128; }
    else if (t < 387072) { l = 2; off = 368640; W = 96;  H = 64;  }
    else if (t < 391680) { l = 3; off = 387072; W = 48;  H = 32;  }
    else                 { l = 4; off = 391680; W = 24;  H = 16;  }
}

__device__ __forceinline__ void slice_info(int s, int& l, int& sl) {
    if (s < 18)      { l = 0; sl = s; }
    else if (s < 23) { l = 1; sl = s - 18; }
    else if (s < 25) { l = 2; sl = s - 23; }
    else if (s < 26) { l = 3; sl = s - 25; }
    else             { l = 4; sl = s - 26; }
}

__device__ __forceinline__ void lvl_consts(int l, int& len, int& off, int& HW) {
    switch (l) {
    case 0: len = 294912; off = 0;      HW = 98304; break;
    case 1: len = 73728;  off = 294912; HW = 24576; break;
    case 2: len = 18432;  off = 368640; HW = 6144;  break;
    case 3: len = 4608;   off = 387072; HW = 1536;  break;
    default: len = 1152;  off = 391680; HW = 384;   break;
    }
}

__device__ __forceinline__ void lvl_slices(int l, int& sbase, int& nsl) {
    switch (l) {
    case 0: sbase = 0;  nsl = 18; break;
    case 1: sbase = 18; nsl = 5;  break;
    case 2: sbase = 23; nsl = 2;  break;
    case 3: sbase = 25; nsl = 1;  break;
    default: sbase = 26; nsl = 1; break;
    }
}

// Decode one proposal exactly as the reference (f32, no FMA contraction).
__device__ void decode_one(const Ptrs& P, int n, int t, float bx[4], bool& valid, int& lvl) {
#pragma clang fp contract(off)
    int l, off, W, H;
    lvl_info(t, l, off, W, H);
    lvl = l;
    int i = t - off;
    int a = i % 3;
    int p = i / 3;
    int y = p / W, x = p - y * W;
    const float* D = P.del[l];
    size_t plane = (size_t)W * H;
    size_t base = ((size_t)n * 12 + (size_t)a * 4) * plane + (size_t)y * W + x;
    float dx = D[base];
    float dy = D[base + plane];
    float dw = D[base + 2 * plane];
    float dh = D[base + 3 * plane];
    const float* an = P.anch + (size_t)t * 4;
    float a0 = an[0], a1 = an[1], a2 = an[2], a3 = an[3];
    float wa = a2 - a0, ha = a3 - a1;
    float cxa = a0 + 0.5f * wa, cya = a1 + 0.5f * ha;
    const float CLIP = 4.135166556742356f;  // log(1000/16) rounded to f32
    dw = fminf(dw, CLIP);
    dh = fminf(dh, CLIP);
    float cx = dx * wa + cxa;
    float cy = dy * ha + cya;
    float pw = expf(dw) * wa;
    float ph = expf(dh) * ha;
    float x1 = cx - 0.5f * pw, y1 = cy - 0.5f * ph;
    float x2 = cx + 0.5f * pw, y2 = cy + 0.5f * ph;
    x1 = fminf(fmaxf(x1, 0.f), 1536.f);
    x2 = fminf(fmaxf(x2, 0.f), 1536.f);
    y1 = fminf(fmaxf(y1, 0.f), 1024.f);
    y2 = fminf(fmaxf(y2, 0.f), 1024.f);
    bx[0] = x1; bx[1] = y1; bx[2] = x2; bx[3] = y2;
    valid = ((x2 - x1) >= 1e-3f) && ((y2 - y1) >= 1e-3f);
}

__global__ void k_zero_out(float* out, int n) {
    int i = blockIdx.x * blockDim.x + threadIdx.x;
    if (i < n) out[i] = 0.f;
}

__global__ void k_zero32(unsigned* p, int n) {
    int i = blockIdx.x * blockDim.x + threadIdx.x;
    if (i < n) p[i] = 0u;
}

// Per-slice 12-bit histogram straight from obj tensors.
__global__ __launch_bounds__(256) void k_hist(Ptrs P, unsigned* ghist) {
    int img = blockIdx.x / NSLICE, s = blockIdx.x % NSLICE;
    int l, sl; slice_info(s, l, sl);
    int len, off, HW; lvl_consts(l, len, off, HW);
    int start = sl * SLICE;
    int cnt4 = min(SLICE, len - start) >> 2;
    const uint4* S4 = (const uint4*)(P.obj[l] + (size_t)img * 3 * HW + start);
    __shared__ unsigned hist[2 * HCOPY];
    int t = threadIdx.x;
    for (int i = t; i < 2 * HCOPY; i += 256) hist[i] = 0u;
    __syncthreads();
    unsigned* myh = hist + (t & 1) * HCOPY;
    for (int i = t; i < cnt4; i += 256) {
        uint4 v = S4[i];
        atomicAdd(&myh[flipb(v.x) >> 20], 1u);
        atomicAdd(&myh[flipb(v.y) >> 20], 1u);
        atomicAdd(&myh[flipb(v.z) >> 20], 1u);
        atomicAdd(&myh[flipb(v.w) >> 20], 1u);
    }
    __syncthreads();
    unsigned* G = ghist + (size_t)(img * 5 + l) * 4096;
    for (int b = t; b < 4096; b += 256) {
        unsigned v = hist[b] + hist[HCOPY + b];
        if (v) atomicAdd(&G[b], v);
    }
}

// Per-task pivot find (suffix scan over the 4096-bin global histogram).
__global__ __launch_bounds__(1024) void k_pivot(const unsigned* ghist, uint2* pivinfo,
                                                int* vcnt) {
    int task = blockIdx.x;
    int t = threadIdx.x;
    if (task == 0 && t < N_IMGS) vcnt[t] = KSEL;
    __shared__ unsigned hl[4096];
    __shared__ unsigned suf[1024];
    const unsigned* H = ghist + (size_t)task * 4096;
    for (int i = t; i < 4096; i += 1024) hl[i] = H[i];
    __syncthreads();
    suf[t] = hl[4 * t] + hl[4 * t + 1] + hl[4 * t + 2] + hl[4 * t + 3];
    for (int d = 1; d < 1024; d <<= 1) {
        __syncthreads();
        unsigned v = (t + d < 1024) ? suf[t + d] : 0u;
        __syncthreads();
        suf[t] += v;
    }
    __syncthreads();
    unsigned above = (t == 1023) ? 0u : suf[t + 1];
    if (suf[t] >= PRE_K && above < PRE_K) {
        int b = 4 * t + 3;
        unsigned c = above;
        while (c + hl[b] < PRE_K) { c += hl[b]; --b; }
        pivinfo[task] = make_uint2((unsigned)b, PRE_K - c);
    }
}

// Phase A: per-wave hit counts, register-only in the loop.
__global__ __launch_bounds__(256) void k_cnt(Ptrs P, const uint2* pivinfo,
                                             unsigned* cntgt, unsigned* cnteq) {
    int img = blockIdx.x / NSLICE, s = blockIdx.x % NSLICE;
    int l, sl; slice_info(s, l, sl);
    int len, off, HW; lvl_consts(l, len, off, HW);
    int start = sl * SLICE;
    int cnt4 = min(SLICE, len - start) >> 2;
    int task = img * 5 + l;
    unsigned pivot = pivinfo[task].x;
    const uint4* S4 = (const uint4*)(P.obj[l] + (size_t)img * 3 * HW + start);
    int t = threadIdx.x, lane = t & 63, wv = t >> 6;
    unsigned cg = 0u, ce = 0u;
    for (int i = t; i < cnt4; i += 256) {
        uint4 v = S4[i];
        unsigned vv[4] = {v.x, v.y, v.z, v.w};
#pragma unroll
        for (int q = 0; q < 4; ++q) {
            unsigned b = flipb(vv[q]) >> 20;
            cg += (b > pivot);
            ce += (b == pivot);
        }
    }
    for (int d = 1; d < 64; d <<= 1) {
        cg += (unsigned)__shfl_xor((int)cg, d, 64);
        ce += (unsigned)__shfl_xor((int)ce, d, 64);
    }
    if (lane == 0) {
        int ws = blockIdx.x * 4 + wv;
        cntgt[ws] = cg;
        cnteq[ws] = ce;
    }
}

// Phase B: per-task exclusive scan of wave counts -> base offsets; nc = eq total.
__global__ __launch_bounds__(128) void k_off(const unsigned* cntgt, const unsigned* cnteq,
                                             unsigned* basegt, unsigned* baseeq, int* nc) {
    int task = blockIdx.x;
    int img = task / 5, l = task % 5;
    int sbase, nsl; lvl_slices(l, sbase, nsl);
    int nws = nsl * 4;
    int wsbase = (img * NSLICE + sbase) * 4;
    __shared__ unsigned sg[128], se[128];
    int t = threadIdx.x;
    unsigned g0 = (t < nws) ? cntgt[wsbase + t] : 0u;
    unsigned e0 = (t < nws) ? cnteq[wsbase + t] : 0u;
    sg[t] = g0; se[t] = e0;
    for (int d = 1; d < 128; d <<= 1) {
        __syncthreads();
        unsigned ag = (t >= d) ? sg[t - d] : 0u;
        unsigned ae = (t >= d) ? se[t - d] : 0u;
        __syncthreads();
        sg[t] += ag; se[t] += ae;
    }
    __syncthreads();
    if (t < nws) {
        basegt[wsbase + t] = sg[t] - g0;   // exclusive prefix
        baseeq[wsbase + t] = se[t] - e0;
    }
    if (t == 0) nc[task] = (int)se[127];   // total eq (pads contribute 0)
}

// Phase C: re-read, ballot-prefix slot assignment (no atomics).
__global__ __launch_bounds__(256) void k_write(Ptrs P, const uint2* pivinfo,
                                               const unsigned* basegt, const unsigned* baseeq,
                                               uint2* sel, u64* cand) {
    int img = blockIdx.x / NSLICE, s = blockIdx.x % NSLICE;
    int l, sl; slice_info(s, l, sl);
    int len, off, HW; lvl_consts(l, len, off, HW);
    int start = sl * SLICE;
    int cnt4 = min(SLICE, len - start) >> 2;
    int task = img * 5 + l;
    unsigned pivot = pivinfo[task].x;
    const uint4* S4 = (const uint4*)(P.obj[l] + (size_t)img * 3 * HW + start);
    uint2* out = sel + (size_t)task * PRE_K;
    u64* cd = cand + (size_t)task * CANDMAX;
    int t = threadIdx.x, lane = t & 63, wv = t >> 6;
    int ws = blockIdx.x * 4 + wv;
    unsigned og = basegt[ws], oe = baseeq[ws];
    u64 below = (1ull << lane) - 1ull;
    int iters = (cnt4 + 255) >> 8;
    uint4 nxt = (t < cnt4) ? S4[t] : make_uint4(0u, 0u, 0u, 0u);
    for (int it = 0; it < iters; ++it) {
        int ii = it * 256 + t;
        bool live = ii < cnt4;
        uint4 cur = nxt;
        int jj = (it + 1) * 256 + t;
        if (it + 1 < iters) nxt = (jj < cnt4) ? S4[jj] : make_uint4(0u, 0u, 0u, 0u);
        unsigned vv[4] = {cur.x, cur.y, cur.z, cur.w};
#pragma unroll
        for (int q = 0; q < 4; ++q) {
            unsigned u = flipb(vv[q]);
            unsigned b = u >> 20;
            bool gt = live && (b > pivot);
            bool eq = live && (b == pivot);
            unsigned tf = 0u;
            if (gt || eq) {
                int i = start + 4 * ii + q;
                int a = i / HW, rem = i - a * HW;
                tf = (unsigned)(off + rem * 3 + a);
            }
            u64 mg = __ballot((int)gt);
            if (gt) out[og + (unsigned)__popcll(mg & below)] = make_uint2(u, tf);
            og += (unsigned)__popcll(mg);
            u64 me = __ballot((int)eq);
            if (eq) {
                unsigned slot = oe + (unsigned)__popcll(me & below);
                if (slot < CANDMAX) cd[slot] = ((u64)u << 32) | (u64)tf;
            }
            oe += (unsigned)__popcll(me);
        }
    }
}

// Exact rank among pivot-bin candidates (lax.top_k tie semantics).
__global__ __launch_bounds__(1024) void k_rank(const uint2* pivinfo, const u64* cand,
                                               const int* nc, uint2* sel) {
    int task = blockIdx.x;
    int t = threadIdx.x;
    int C = min(nc[task], CANDMAX);
    int krem = (int)pivinfo[task].y;
    int nbase = PRE_K - krem;
    __shared__ u64 lc[CANDMAX];
    const u64* cd = cand + (size_t)task * CANDMAX;
    for (int i = t; i < C; i += 1024) lc[i] = cd[i];
    __syncthreads();
    uint2* out = sel + (size_t)task * PRE_K;
    for (int i = t; i < C; i += 1024) {
        u64 a = lc[i];
        unsigned vi = (unsigned)(a >> 32), xi = (unsigned)a;
        int rank = 0;
        for (int j = 0; j < C; ++j) {
            u64 bj = lc[j];
            unsigned vj = (unsigned)(bj >> 32), xj = (unsigned)bj;
            rank += (vj > vi) || (vj == vi && xj < xi);
        }
        if (rank < krem) out[nbase + rank] = make_uint2(vi, xi);
    }
}

// Fused key-build + per-(image,level) bitonic sort of 1024-padded list.
__global__ __launch_bounds__(1024) void k_sort1(Ptrs P, const uint2* sel, u64* keys2) {
    __shared__ u64 s[LPAD];
    int task = blockIdx.x;          // n*5 + l
    int n = task / 5;
    int t = threadIdx.x;
    u64 key = ~0ull;
    if (t < PRE_K) {
        uint2 sv = sel[(size_t)task * PRE_K + t];
        float bx[4]; bool valid; int lv;
        decode_one(P, n, (int)sv.y, bx, valid, lv);
        key = valid ? (((u64)(~sv.x) << 32) | (u64)sv.y)
                    : (0xFFFFFFFF00000000ull | (u64)sv.y);
    }
    s[t] = key;
    for (int k = 2; k <= LPAD; k <<= 1) {
        for (int j = k >> 1; j > 0; j >>= 1) {
            __syncthreads();
            int ixj = t ^ j;
            if (ixj > t) {
                u64 a = s[t], b = s[ixj];
                bool asc = ((t & k) == 0);
                if (asc ? (a > b) : (a < b)) { s[t] = b; s[ixj] = a; }
            }
        }
    }
    __syncthreads();
    keys2[(size_t)task * LPAD + t] = s[t];
}

// Fused stable 5-way merge-by-rank + decode + scatter.
__global__ void k_mergedec(Ptrs P, const u64* keys2,
                           float4* boxes, float4* nboxes, int* vcnt) {
    int idx = blockIdx.x * blockDim.x + threadIdx.x;
    if (idx >= N_IMGS * MSLOTS) return;
    int n = idx / MSLOTS, slot = idx - n * MSLOTS;
    int l = slot >> 10, p = slot & (LPAD - 1);
    const u64* base = keys2 + (size_t)n * MSLOTS;
    u64 key = base[(size_t)l * LPAD + p];
    if (key == ~0ull) return;       // pad slot
    int rank = p;
#pragma unroll
    for (int m = 0; m < NLVL; ++m) {
        if (m == l) continue;
        const u64* L = base + (size_t)m * LPAD;
        bool le = (m < l);
        int lo = 0, hi = LPAD;
        while (lo < hi) {
            int mid = (lo + hi) >> 1;
            u64 v = L[mid];
            bool take = le ? (v <= key) : (v < key);
            if (take) lo = mid + 1; else hi = mid;
        }
        rank += lo;
    }
    if (rank >= KSEL) return;
    int oidx = n * KSEL + rank;
    if ((key >> 32) == 0xFFFFFFFFull) {
        boxes[oidx] = make_float4(0.f, 0.f, 0.f, 0.f);
        nboxes[oidx] = make_float4(0.f, 0.f, 0.f, 0.f);
        atomicMin(&vcnt[n], rank);
        return;
    }
    int t = (int)(key & 0xFFFFFFFFull);
    float bx[4]; bool valid; int lv;
    decode_one(P, n, t, bx, valid, lv);
    boxes[oidx] = make_float4(bx[0], bx[1], bx[2], bx[3]);
    float offv = (float)lv * 1537.0f;   // (max(H,W)+1) * level
    nboxes[oidx] = make_float4(bx[0] + offv, bx[1] + offv, bx[2] + offv, bx[3] + offv);
}

// Suppression bitmask, ballot form, 2 col-blocks per wave (round-13 notes).
// TRANSPOSED layout: maskT[(n*MASKW + cword)*MROWS + r]; upper halves only.
__device__ __forceinline__ float rdlane(float v, int src) {
    return __int_as_float(__builtin_amdgcn_readlane(__float_as_int(v), src));
}
__global__ __launch_bounds__(64) void k_mask(const float4* __restrict__ nboxes,
                                             u64* __restrict__ maskT) {
#pragma clang fp contract(off)
    int rb = blockIdx.x, cs = blockIdx.y, n = blockIdx.z;
    int cb0 = cs * 2, cb1 = cb0 + 1;
    if (cb1 < rb) return;           // whole superblock below diagonal
    int lane = threadIdx.x;
    int r0 = rb * 64;
    const float4 z4 = make_float4(0.f, 0.f, 0.f, 0.f);
    const float4* B = nboxes + (size_t)n * KSEL;
    float4 rbx = (r0 + lane < KSEL) ? B[r0 + lane] : z4;
    float areaR = (rbx.z - rbx.x) * (rbx.w - rbx.y);
    float4 cA = (cb0 * 64 + lane < KSEL) ? B[cb0 * 64 + lane] : z4;
    float4 cB = (cb1 * 64 + lane < KSEL && cb1 < MASKW) ? B[cb1 * 64 + lane] : z4;
    float aCA = (cA.z - cA.x) * (cA.w - cA.y);
    float aCB = (cB.z - cB.x) * (cB.w - cB.y);
    u64 cmA = __ballot(cb0 * 64 + lane < KSEL);
    u64 cmB = __ballot(cb1 * 64 + lane < KSEL && cb1 < MASKW);
    const double MID = 0x1.666667p-1;
    u64 wA = 0ull, wB = 0ull;
#pragma unroll 4
    for (int rr = 0; rr < 64; ++rr) {
        float rx1 = rdlane(rbx.x, rr), ry1 = rdlane(rbx.y, rr);
        float rx2 = rdlane(rbx.z, rr), ry2 = rdlane(rbx.w, rr);
        float aR  = rdlane(areaR, rr);
        float wvA = fmaxf(fminf(rx2, cA.z) - fmaxf(rx1, cA.x), 0.f);
        float hvA = fmaxf(fminf(ry2, cA.w) - fmaxf(ry1, cA.y), 0.f);
        float inA = wvA * hvA;
        float unA = (aR + aCA) - inA;
        bool supA = (double)inA >= MID * (double)unA;
        float wvB = fmaxf(fminf(rx2, cB.z) - fmaxf(rx1, cB.x), 0.f);
        float hvB = fmaxf(fminf(ry2, cB.w) - fmaxf(ry1, cB.y), 0.f);
        float inB = wvB * hvB;
        float unB = (aR + aCB) - inB;
        bool supB = (double)inB >= MID * (double)unB;
        u64 a = __ballot((int)supA) & cmA;
        u64 b = __ballot((int)supB) & cmB;
        u64 dm = ~((2ull << rr) - 1ull);
        if (rb == cb0) a &= dm;
        if (rb == cb1) b &= dm;
        wA = (lane == rr) ? a : wA;
        wB = (lane == rr) ? b : wB;
    }
    if (r0 + lane < KSEL) {
        if (cb0 >= rb)
            maskT[((size_t)n * MASKW + cb0) * MROWS + r0 + lane] = wA;
        if (cb1 < MASKW)
            maskT[((size_t)n * MASKW + cb1) * MROWS + r0 + lane] = wB;
    }
}

__device__ __forceinline__ u64 bcast64(u64 v, int src) {
    unsigned lo = (unsigned)__builtin_amdgcn_readlane((int)(unsigned)v, src);
    unsigned hi = (unsigned)__builtin_amdgcn_readlane((int)(unsigned)(v >> 32), src);
    return ((u64)hi << 32) | (u64)lo;
}

// Wave64 OR-reduce via DPP, result in lane 63.
__device__ __forceinline__ unsigned or_red_dpp(unsigned v) {
    v |= (unsigned)__builtin_amdgcn_update_dpp(0, (int)v, 0x111, 0xf, 0xf, true);
    v |= (unsigned)__builtin_amdgcn_update_dpp(0, (int)v, 0x112, 0xf, 0xf, true);
    v |= (unsigned)__builtin_amdgcn_update_dpp(0, (int)v, 0x114, 0xf, 0xf, true);
    v |= (unsigned)__builtin_amdgcn_update_dpp(0, (int)v, 0x118, 0xf, 0xf, true);
    v |= (unsigned)__builtin_amdgcn_update_dpp(0, (int)v, 0x142, 0xa, 0xf, false);
    v |= (unsigned)__builtin_amdgcn_update_dpp(0, (int)v, 0x143, 0xc, 0xf, false);
    return v;
}

// Single-wave greedy NMS scan, fully software-pipelined (round-8 design, the
// proven 98 us version): all loads for chunk c issued during chunk c-1 so the
// per-chunk critical path is VALU/SALU only (DPP OR-reduce + ctz chain).
//   bulk[16]: word c of rows kept through chunk c-2 (unrolled register gather);
//   nc: word c of ALL rows of chunk c-1 (coalesced), masked by keptbits_{c-1};
//   wc: word c of chunk c's rows (diagonal, coalesced).
__global__ __launch_bounds__(64, 1) void k_scan(const u64* maskT, const int* vcnt,
                                                int* keep, int* nkept) {
    __shared__ int keep_lds[1024];
    int n = blockIdx.x, lane = threadIdx.x;
    int V = vcnt[n];
    const u64* MT = maskT + (size_t)n * MASKW * MROWS;

    for (int i = lane; i < 1024; i += 64) keep_lds[i] = 0;   // single wave: no barrier

    int cnt = 0, cntprev = 0;
    u64 keptprev = 0ull;
    bool full = false;
    int nchunks = (V + 63) >> 6;

    u64 bulk[16];
#pragma unroll
    for (int q = 0; q < 16; ++q) bulk[q] = 0ull;
    u64 wc = MT[lane];      // word 0 of chunk 0 rows
    u64 nc = 0ull;

    for (int c = 0; c < nchunks && !full; ++c) {
        u64 part = 0ull;
#pragma unroll
        for (int q = 0; q < 16; ++q)
            part |= (q * 64 + lane < cntprev) ? bulk[q] : 0ull;
        part |= ((keptprev >> lane) & 1ull) ? nc : 0ull;

        unsigned plo = or_red_dpp((unsigned)part);
        unsigned phi = or_red_dpp((unsigned)(part >> 32));
        u64 cur = ((u64)(unsigned)__builtin_amdgcn_readlane((int)phi, 63) << 32)
                | (u64)(unsigned)__builtin_amdgcn_readlane((int)plo, 63);

        int cntNow = cnt;
        int colN = (c + 1 < NCHUNK) ? (c + 1) : (NCHUNK - 1);
        const u64* colNp = MT + (size_t)colN * MROWS;
        {
            int kr[16];
#pragma unroll
            for (int q = 0; q < 16; ++q) kr[q] = keep_lds[q * 64 + lane];
#pragma unroll
            for (int q = 0; q < 16; ++q) bulk[q] = colNp[kr[q]];
        }
        u64 nc_next = colNp[(size_t)c * 64 + lane];
        u64 wc_next = colNp[(size_t)colN * 64 + lane];

        int base = c * 64;
        int jmax = V - base; if (jmax > 64) jmax = 64;
        u64 avail = ~cur;
        if (jmax < 64) avail &= (1ull << jmax) - 1ull;
        while (avail) {
            int j = __builtin_ctzll(avail);
            if (lane == 0) keep_lds[cnt] = base + j;
            ++cnt;
            if (cnt == POST_K) { full = true; break; }
            u64 wcj = bcast64(wc, j);
            avail &= avail - 1;
            avail &= ~wcj;
        }
        keptprev = 0ull;
        for (int i = cntNow + (int)lane; i < cnt; i += 64) {
            int r = keep_lds[i];
            keptprev |= 1ull << (r - base);
        }
        {
            unsigned klo = or_red_dpp((unsigned)keptprev);
            unsigned khi = or_red_dpp((unsigned)(keptprev >> 32));
            keptprev = ((u64)(unsigned)__builtin_amdgcn_readlane((int)khi, 63) << 32)
                     | (u64)(unsigned)__builtin_amdgcn_readlane((int)klo, 63);
        }
        cntprev = cntNow;
        wc = wc_next;
        nc = nc_next;
    }

    for (int i = lane; i < cnt; i += 64) keep[n * POST_K + i] = keep_lds[i];
    if (lane == 0) nkept[n] = cnt;
}

__global__ void k_out(const float4* boxes, const int* keep, const int* nkept, float4* out) {
    int idx = blockIdx.x * blockDim.x + threadIdx.x;
    if (idx >= N_IMGS * POST_K) return;
    int n = idx / POST_K, k = idx - n * POST_K;
    float4 v = make_float4(0.f, 0.f, 0.f, 0.f);
    if (k < nkept[n]) v = boxes[(size_t)n * KSEL + keep[n * POST_K + k]];
    out[idx] = v;
}

extern "C" void kernel_launch(void* const* d_in, const int* in_sizes, int n_in,
                              void* d_out, int out_size, void* d_ws, size_t ws_size,
                              hipStream_t stream) {
    // dict order: obj0, delta0, obj1, delta1, ..., obj4, delta4, anchors
    Ptrs P;
    for (int l = 0; l < 5; ++l) {
        P.obj[l] = (const float*)d_in[2 * l];
        P.del[l] = (const float*)d_in[2 * l + 1];
    }
    P.anch = (const float*)d_in[10];

    // workspace carve
    size_t o = 0;
    auto alloc = [&](size_t bytes) {
        size_t cur = o;
        o = (o + bytes + 255) & ~(size_t)255;
        return cur;
    };
    size_t off_gh     = alloc((size_t)GH_U32 * 4);
    size_t off_cnt    = alloc((size_t)NWS * 4 * 4);   // cntgt, cnteq, basegt, baseeq
    size_t off_nc     = alloc(64 * 4);
    size_t off_piv    = alloc((size_t)N_IMGS * NLVL * 8);
    size_t off_cand   = alloc((size_t)N_IMGS * NLVL * CANDMAX * 8);
    size_t off_sel    = alloc((size_t)N_IMGS * KSEL * 8);
    size_t off_keys2  = alloc((size_t)N_IMGS * MSLOTS * 8);
    size_t off_boxes  = alloc((size_t)N_IMGS * KSEL * 16);
    size_t off_nbox   = alloc((size_t)N_IMGS * KSEL * 16);
    size_t off_mask   = alloc((size_t)N_IMGS * MASKW * MROWS * 8);
    size_t off_vcnt   = alloc(N_IMGS * 4);
    size_t off_keep   = alloc((size_t)N_IMGS * POST_K * 4);
    size_t off_nkept  = alloc(N_IMGS * 4);

    float* out = (float*)d_out;
    if (o > ws_size) {  // workspace too small: emit zeros (visible failure, no crash)
        k_zero_out<<<(out_size + 255) / 256, 256, 0, stream>>>(out, out_size);
        return;
    }

    char* w = (char*)d_ws;
    unsigned* ghist  = (unsigned*)(w + off_gh);
    unsigned* cntgt  = (unsigned*)(w + off_cnt);
    unsigned* cnteq  = cntgt + NWS;
    unsigned* basegt = cntgt + 2 * NWS;
    unsigned* baseeq = cntgt + 3 * NWS;
    int* nc          = (int*)(w + off_nc);
    uint2* pivinfo   = (uint2*)(w + off_piv);
    u64* cand        = (u64*)(w + off_cand);
    uint2* sel       = (uint2*)(w + off_sel);
    u64* keys2       = (u64*)(w + off_keys2);
    float4* boxes    = (float4*)(w + off_boxes);
    float4* nboxes   = (float4*)(w + off_nbox);
    u64* maskT       = (u64*)(w + off_mask);
    int* vcnt        = (int*)(w + off_vcnt);
    int* keep        = (int*)(w + off_keep);
    int* nkept       = (int*)(w + off_nkept);

    k_zero32<<<(GH_U32 + 255) / 256, 256, 0, stream>>>(ghist, GH_U32);
    k_hist<<<N_IMGS * NSLICE, 256, 0, stream>>>(P, ghist);
    k_pivot<<<N_IMGS * NLVL, 1024, 0, stream>>>(ghist, pivinfo, vcnt);
    k_cnt<<<N_IMGS * NSLICE, 256, 0, stream>>>(P, pivinfo, cntgt, cnteq);
    k_off<<<N_IMGS * NLVL, 128, 0, stream>>>(cntgt, cnteq, basegt, baseeq, nc);
    k_write<<<N_IMGS * NSLICE, 256, 0, stream>>>(P, pivinfo, basegt, baseeq, sel, cand);
    k_rank<<<N_IMGS * NLVL, 1024, 0, stream>>>(pivinfo, cand, nc, sel);
    k_sort1<<<N_IMGS * NLVL, 1024, 0, stream>>>(P, sel, keys2);
    k_mergedec<<<(N_IMGS * MSLOTS + 255) / 256, 256, 0, stream>>>(P, keys2, boxes, nboxes, vcnt);
    k_mask<<<dim3(NCHUNK, (MASKW + 1) / 2, N_IMGS), 64, 0, stream>>>(nboxes, maskT);
    k_scan<<<N_IMGS, 64, 0, stream>>>(maskT, vcnt, keep, nkept);
    k_out<<<(N_IMGS * POST_K + 255) / 256, 256, 0, stream>>>((const float4*)boxes, keep, nkept, (float4*)d_out);
}

// Round 22
// 291.974 us; speedup vs baseline: 1.9538x; 1.0197x over previous
//
#include <hip/hip_runtime.h>
#include <stdint.h>

#define N_IMGS 8
#define NLVL 5
#define TOT 392832          // total anchors across levels
#define PRE_K 1000
#define POST_K 1000
#define KSEL 5000           // 5 levels * 1000
#define MASKW 79            // ceil(5000/64)
#define MROWS 5056          // KSEL padded to 79 full 64-row chunks
#define NCHUNK 79
#define LPAD 1024           // per-level padded list length
#define MSLOTS (NLVL * LPAD)
#define HCOPY 4100          // 4096 bins + 4 pad
#define CANDMAX 4096
#define SLICE 16384         // elements per hist/compact slice
#define NSLICE 27           // slices per image: 18+5+2+1+1
#define NWS (N_IMGS * NSLICE * 4)   // wave-slots for counting
#define GH_U32 (N_IMGS * NLVL * 4096)

typedef unsigned long long u64;

struct Ptrs {
    const float* obj[5];
    const float* del[5];
    const float* anch;
};

__device__ __forceinline__ unsigned flipb(unsigned u) {
    return (u & 0x80000000u) ? ~u : (u | 0x80000000u);
}

__device__ __forceinline__ void lvl_info(int t, int& l, int& off, int& W, int& H) {
    if (t < 294912)      { l = 0; off = 0;      W = 384; H = 256; }
    else if (t < 368640) { l = 1; off = 294912; W = 192; H = 128; }
    else if (t < 387072) { l = 2; off = 368640; W = 96;  H = 64;  }
    else if (t < 391680) { l = 3; off = 387072; W = 48;  H = 32;  }
    else                 { l = 4; off = 391680; W = 24;  H = 16;  }
}

__device__ __forceinline__ void slice_info(int s, int& l, int& sl) {
    if (s < 18)      { l = 0; sl = s; }
    else if (s < 23) { l = 1; sl = s - 18; }
    else if (s < 25) { l = 2; sl = s - 23; }
    else if (s < 26) { l = 3; sl = s - 25; }
    else             { l = 4; sl = s - 26; }
}

__device__ __forceinline__ void lvl_consts(int l, int& len, int& off, int& HW) {
    switch (l) {
    case 0: len = 294912; off = 0;      HW = 98304; break;
    case 1: len = 73728;  off = 294912; HW = 24576; break;
    case 2: len = 18432;  off = 368640; HW = 6144;  break;
    case 3: len = 4608;   off = 387072; HW = 1536;  break;
    default: len = 1152;  off = 391680; HW = 384;   break;
    }
}

__device__ __forceinline__ void lvl_slices(int l, int& sbase, int& nsl) {
    switch (l) {
    case 0: sbase = 0;  nsl = 18; break;
    case 1: sbase = 18; nsl = 5;  break;
    case 2: sbase = 23; nsl = 2;  break;
    case 3: sbase = 25; nsl = 1;  break;
    default: sbase = 26; nsl = 1; break;
    }
}

// Decode one proposal exactly as the reference (f32, no FMA contraction).
__device__ void decode_one(const Ptrs& P, int n, int t, float bx[4], bool& valid, int& lvl) {
#pragma clang fp contract(off)
    int l, off, W, H;
    lvl_info(t, l, off, W, H);
    lvl = l;
    int i = t - off;
    int a = i % 3;
    int p = i / 3;
    int y = p / W, x = p - y * W;
    const float* D = P.del[l];
    size_t plane = (size_t)W * H;
    size_t base = ((size_t)n * 12 + (size_t)a * 4) * plane + (size_t)y * W + x;
    float dx = D[base];
    float dy = D[base + plane];
    float dw = D[base + 2 * plane];
    float dh = D[base + 3 * plane];
    const float* an = P.anch + (size_t)t * 4;
    float a0 = an[0], a1 = an[1], a2 = an[2], a3 = an[3];
    float wa = a2 - a0, ha = a3 - a1;
    float cxa = a0 + 0.5f * wa, cya = a1 + 0.5f * ha;
    const float CLIP = 4.135166556742356f;  // log(1000/16) rounded to f32
    dw = fminf(dw, CLIP);
    dh = fminf(dh, CLIP);
    float cx = dx * wa + cxa;
    float cy = dy * ha + cya;
    float pw = expf(dw) * wa;
    float ph = expf(dh) * ha;
    float x1 = cx - 0.5f * pw, y1 = cy - 0.5f * ph;
    float x2 = cx + 0.5f * pw, y2 = cy + 0.5f * ph;
    x1 = fminf(fmaxf(x1, 0.f), 1536.f);
    x2 = fminf(fmaxf(x2, 0.f), 1536.f);
    y1 = fminf(fmaxf(y1, 0.f), 1024.f);
    y2 = fminf(fmaxf(y2, 0.f), 1024.f);
    bx[0] = x1; bx[1] = y1; bx[2] = x2; bx[3] = y2;
    valid = ((x2 - x1) >= 1e-3f) && ((y2 - y1) >= 1e-3f);
}

__global__ void k_zero_out(float* out, int n) {
    int i = blockIdx.x * blockDim.x + threadIdx.x;
    if (i < n) out[i] = 0.f;
}

__global__ void k_zero32(unsigned* p, int n) {
    int i = blockIdx.x * blockDim.x + threadIdx.x;
    if (i < n) p[i] = 0u;
}

// Per-slice 12-bit histogram straight from obj tensors.
__global__ __launch_bounds__(256) void k_hist(Ptrs P, unsigned* ghist) {
    int img = blockIdx.x / NSLICE, s = blockIdx.x % NSLICE;
    int l, sl; slice_info(s, l, sl);
    int len, off, HW; lvl_consts(l, len, off, HW);
    int start = sl * SLICE;
    int cnt4 = min(SLICE, len - start) >> 2;
    const uint4* S4 = (const uint4*)(P.obj[l] + (size_t)img * 3 * HW + start);
    __shared__ unsigned hist[2 * HCOPY];
    int t = threadIdx.x;
    for (int i = t; i < 2 * HCOPY; i += 256) hist[i] = 0u;
    __syncthreads();
    unsigned* myh = hist + (t & 1) * HCOPY;
    for (int i = t; i < cnt4; i += 256) {
        uint4 v = S4[i];
        atomicAdd(&myh[flipb(v.x) >> 20], 1u);
        atomicAdd(&myh[flipb(v.y) >> 20], 1u);
        atomicAdd(&myh[flipb(v.z) >> 20], 1u);
        atomicAdd(&myh[flipb(v.w) >> 20], 1u);
    }
    __syncthreads();
    unsigned* G = ghist + (size_t)(img * 5 + l) * 4096;
    for (int b = t; b < 4096; b += 256) {
        unsigned v = hist[b] + hist[HCOPY + b];
        if (v) atomicAdd(&G[b], v);
    }
}

// Per-task pivot find (suffix scan over the 4096-bin global histogram).
__global__ __launch_bounds__(1024) void k_pivot(const unsigned* ghist, uint2* pivinfo,
                                                int* vcnt) {
    int task = blockIdx.x;
    int t = threadIdx.x;
    if (task == 0 && t < N_IMGS) vcnt[t] = KSEL;
    __shared__ unsigned hl[4096];
    __shared__ unsigned suf[1024];
    const unsigned* H = ghist + (size_t)task * 4096;
    for (int i = t; i < 4096; i += 1024) hl[i] = H[i];
    __syncthreads();
    suf[t] = hl[4 * t] + hl[4 * t + 1] + hl[4 * t + 2] + hl[4 * t + 3];
    for (int d = 1; d < 1024; d <<= 1) {
        __syncthreads();
        unsigned v = (t + d < 1024) ? suf[t + d] : 0u;
        __syncthreads();
        suf[t] += v;
    }
    __syncthreads();
    unsigned above = (t == 1023) ? 0u : suf[t + 1];
    if (suf[t] >= PRE_K && above < PRE_K) {
        int b = 4 * t + 3;
        unsigned c = above;
        while (c + hl[b] < PRE_K) { c += hl[b]; --b; }
        pivinfo[task] = make_uint2((unsigned)b, PRE_K - c);
    }
}

// Phase A: per-wave hit counts, register-only in the loop.
__global__ __launch_bounds__(256) void k_cnt(Ptrs P, const uint2* pivinfo,
                                             unsigned* cntgt, unsigned* cnteq) {
    int img = blockIdx.x / NSLICE, s = blockIdx.x % NSLICE;
    int l, sl; slice_info(s, l, sl);
    int len, off, HW; lvl_consts(l, len, off, HW);
    int start = sl * SLICE;
    int cnt4 = min(SLICE, len - start) >> 2;
    int task = img * 5 + l;
    unsigned pivot = pivinfo[task].x;
    const uint4* S4 = (const uint4*)(P.obj[l] + (size_t)img * 3 * HW + start);
    int t = threadIdx.x, lane = t & 63, wv = t >> 6;
    unsigned cg = 0u, ce = 0u;
    for (int i = t; i < cnt4; i += 256) {
        uint4 v = S4[i];
        unsigned vv[4] = {v.x, v.y, v.z, v.w};
#pragma unroll
        for (int q = 0; q < 4; ++q) {
            unsigned b = flipb(vv[q]) >> 20;
            cg += (b > pivot);
            ce += (b == pivot);
        }
    }
    for (int d = 1; d < 64; d <<= 1) {
        cg += (unsigned)__shfl_xor((int)cg, d, 64);
        ce += (unsigned)__shfl_xor((int)ce, d, 64);
    }
    if (lane == 0) {
        int ws = blockIdx.x * 4 + wv;
        cntgt[ws] = cg;
        cnteq[ws] = ce;
    }
}

// Phase B: per-task exclusive scan of wave counts -> base offsets; nc = eq total.
__global__ __launch_bounds__(128) void k_off(const unsigned* cntgt, const unsigned* cnteq,
                                             unsigned* basegt, unsigned* baseeq, int* nc) {
    int task = blockIdx.x;
    int img = task / 5, l = task % 5;
    int sbase, nsl; lvl_slices(l, sbase, nsl);
    int nws = nsl * 4;
    int wsbase = (img * NSLICE + sbase) * 4;
    __shared__ unsigned sg[128], se[128];
    int t = threadIdx.x;
    unsigned g0 = (t < nws) ? cntgt[wsbase + t] : 0u;
    unsigned e0 = (t < nws) ? cnteq[wsbase + t] : 0u;
    sg[t] = g0; se[t] = e0;
    for (int d = 1; d < 128; d <<= 1) {
        __syncthreads();
        unsigned ag = (t >= d) ? sg[t - d] : 0u;
        unsigned ae = (t >= d) ? se[t - d] : 0u;
        __syncthreads();
        sg[t] += ag; se[t] += ae;
    }
    __syncthreads();
    if (t < nws) {
        basegt[wsbase + t] = sg[t] - g0;   // exclusive prefix
        baseeq[wsbase + t] = se[t] - e0;
    }
    if (t == 0) nc[task] = (int)se[127];   // total eq (pads contribute 0)
}

// Phase C: re-read, ballot-prefix slot assignment (no atomics).
__global__ __launch_bounds__(256) void k_write(Ptrs P, const uint2* pivinfo,
                                               const unsigned* basegt, const unsigned* baseeq,
                                               uint2* sel, u64* cand) {
    int img = blockIdx.x / NSLICE, s = blockIdx.x % NSLICE;
    int l, sl; slice_info(s, l, sl);
    int len, off, HW; lvl_consts(l, len, off, HW);
    int start = sl * SLICE;
    int cnt4 = min(SLICE, len - start) >> 2;
    int task = img * 5 + l;
    unsigned pivot = pivinfo[task].x;
    const uint4* S4 = (const uint4*)(P.obj[l] + (size_t)img * 3 * HW + start);
    uint2* out = sel + (size_t)task * PRE_K;
    u64* cd = cand + (size_t)task * CANDMAX;
    int t = threadIdx.x, lane = t & 63, wv = t >> 6;
    int ws = blockIdx.x * 4 + wv;
    unsigned og = basegt[ws], oe = baseeq[ws];
    u64 below = (1ull << lane) - 1ull;
    int iters = (cnt4 + 255) >> 8;
    uint4 nxt = (t < cnt4) ? S4[t] : make_uint4(0u, 0u, 0u, 0u);
    for (int it = 0; it < iters; ++it) {
        int ii = it * 256 + t;
        bool live = ii < cnt4;
        uint4 cur = nxt;
        int jj = (it + 1) * 256 + t;
        if (it + 1 < iters) nxt = (jj < cnt4) ? S4[jj] : make_uint4(0u, 0u, 0u, 0u);
        unsigned vv[4] = {cur.x, cur.y, cur.z, cur.w};
#pragma unroll
        for (int q = 0; q < 4; ++q) {
            unsigned u = flipb(vv[q]);
            unsigned b = u >> 20;
            bool gt = live && (b > pivot);
            bool eq = live && (b == pivot);
            unsigned tf = 0u;
            if (gt || eq) {
                int i = start + 4 * ii + q;
                int a = i / HW, rem = i - a * HW;
                tf = (unsigned)(off + rem * 3 + a);
            }
            u64 mg = __ballot((int)gt);
            if (gt) out[og + (unsigned)__popcll(mg & below)] = make_uint2(u, tf);
            og += (unsigned)__popcll(mg);
            u64 me = __ballot((int)eq);
            if (eq) {
                unsigned slot = oe + (unsigned)__popcll(me & below);
                if (slot < CANDMAX) cd[slot] = ((u64)u << 32) | (u64)tf;
            }
            oe += (unsigned)__popcll(me);
        }
    }
}

// Exact rank among pivot-bin candidates (lax.top_k tie semantics).
__global__ __launch_bounds__(1024) void k_rank(const uint2* pivinfo, const u64* cand,
                                               const int* nc, uint2* sel) {
    int task = blockIdx.x;
    int t = threadIdx.x;
    int C = min(nc[task], CANDMAX);
    int krem = (int)pivinfo[task].y;
    int nbase = PRE_K - krem;
    __shared__ u64 lc[CANDMAX];
    const u64* cd = cand + (size_t)task * CANDMAX;
    for (int i = t; i < C; i += 1024) lc[i] = cd[i];
    __syncthreads();
    uint2* out = sel + (size_t)task * PRE_K;
    for (int i = t; i < C; i += 1024) {
        u64 a = lc[i];
        unsigned vi = (unsigned)(a >> 32), xi = (unsigned)a;
        int rank = 0;
        for (int j = 0; j < C; ++j) {
            u64 bj = lc[j];
            unsigned vj = (unsigned)(bj >> 32), xj = (unsigned)bj;
            rank += (vj > vi) || (vj == vi && xj < xi);
        }
        if (rank < krem) out[nbase + rank] = make_uint2(vi, xi);
    }
}

// Fused key-build + per-(image,level) bitonic sort of 1024-padded list.
__global__ __launch_bounds__(1024) void k_sort1(Ptrs P, const uint2* sel, u64* keys2) {
    __shared__ u64 s[LPAD];
    int task = blockIdx.x;          // n*5 + l
    int n = task / 5;
    int t = threadIdx.x;
    u64 key = ~0ull;
    if (t < PRE_K) {
        uint2 sv = sel[(size_t)task * PRE_K + t];
        float bx[4]; bool valid; int lv;
        decode_one(P, n, (int)sv.y, bx, valid, lv);
        key = valid ? (((u64)(~sv.x) << 32) | (u64)sv.y)
                    : (0xFFFFFFFF00000000ull | (u64)sv.y);
    }
    s[t] = key;
    for (int k = 2; k <= LPAD; k <<= 1) {
        for (int j = k >> 1; j > 0; j >>= 1) {
            __syncthreads();
            int ixj = t ^ j;
            if (ixj > t) {
                u64 a = s[t], b = s[ixj];
                bool asc = ((t & k) == 0);
                if (asc ? (a > b) : (a < b)) { s[t] = b; s[ixj] = a; }
            }
        }
    }
    __syncthreads();
    keys2[(size_t)task * LPAD + t] = s[t];
}

// Fused stable 5-way merge-by-rank + decode + scatter.
__global__ void k_mergedec(Ptrs P, const u64* keys2,
                           float4* boxes, float4* nboxes, int* vcnt) {
    int idx = blockIdx.x * blockDim.x + threadIdx.x;
    if (idx >= N_IMGS * MSLOTS) return;
    int n = idx / MSLOTS, slot = idx - n * MSLOTS;
    int l = slot >> 10, p = slot & (LPAD - 1);
    const u64* base = keys2 + (size_t)n * MSLOTS;
    u64 key = base[(size_t)l * LPAD + p];
    if (key == ~0ull) return;       // pad slot
    int rank = p;
#pragma unroll
    for (int m = 0; m < NLVL; ++m) {
        if (m == l) continue;
        const u64* L = base + (size_t)m * LPAD;
        bool le = (m < l);
        int lo = 0, hi = LPAD;
        while (lo < hi) {
            int mid = (lo + hi) >> 1;
            u64 v = L[mid];
            bool take = le ? (v <= key) : (v < key);
            if (take) lo = mid + 1; else hi = mid;
        }
        rank += lo;
    }
    if (rank >= KSEL) return;
    int oidx = n * KSEL + rank;
    if ((key >> 32) == 0xFFFFFFFFull) {
        boxes[oidx] = make_float4(0.f, 0.f, 0.f, 0.f);
        nboxes[oidx] = make_float4(0.f, 0.f, 0.f, 0.f);
        atomicMin(&vcnt[n], rank);
        return;
    }
    int t = (int)(key & 0xFFFFFFFFull);
    float bx[4]; bool valid; int lv;
    decode_one(P, n, t, bx, valid, lv);
    boxes[oidx] = make_float4(bx[0], bx[1], bx[2], bx[3]);
    float offv = (float)lv * 1537.0f;   // (max(H,W)+1) * level
    nboxes[oidx] = make_float4(bx[0] + offv, bx[1] + offv, bx[2] + offv, bx[3] + offv);
}

// Suppression bitmask, ballot form, 2 col-blocks per wave (round-13 notes).
// TRANSPOSED layout: maskT[(n*MASKW + cword)*MROWS + r]; upper halves only.
__device__ __forceinline__ float rdlane(float v, int src) {
    return __int_as_float(__builtin_amdgcn_readlane(__float_as_int(v), src));
}
__global__ __launch_bounds__(64) void k_mask(const float4* __restrict__ nboxes,
                                             u64* __restrict__ maskT) {
#pragma clang fp contract(off)
    int rb = blockIdx.x, cs = blockIdx.y, n = blockIdx.z;
    int cb0 = cs * 2, cb1 = cb0 + 1;
    if (cb1 < rb) return;           // whole superblock below diagonal
    int lane = threadIdx.x;
    int r0 = rb * 64;
    const float4 z4 = make_float4(0.f, 0.f, 0.f, 0.f);
    const float4* B = nboxes + (size_t)n * KSEL;
    float4 rbx = (r0 + lane < KSEL) ? B[r0 + lane] : z4;
    float areaR = (rbx.z - rbx.x) * (rbx.w - rbx.y);
    float4 cA = (cb0 * 64 + lane < KSEL) ? B[cb0 * 64 + lane] : z4;
    float4 cB = (cb1 * 64 + lane < KSEL && cb1 < MASKW) ? B[cb1 * 64 + lane] : z4;
    float aCA = (cA.z - cA.x) * (cA.w - cA.y);
    float aCB = (cB.z - cB.x) * (cB.w - cB.y);
    u64 cmA = __ballot(cb0 * 64 + lane < KSEL);
    u64 cmB = __ballot(cb1 * 64 + lane < KSEL && cb1 < MASKW);
    const double MID = 0x1.666667p-1;
    u64 wA = 0ull, wB = 0ull;
#pragma unroll 4
    for (int rr = 0; rr < 64; ++rr) {
        float rx1 = rdlane(rbx.x, rr), ry1 = rdlane(rbx.y, rr);
        float rx2 = rdlane(rbx.z, rr), ry2 = rdlane(rbx.w, rr);
        float aR  = rdlane(areaR, rr);
        float wvA = fmaxf(fminf(rx2, cA.z) - fmaxf(rx1, cA.x), 0.f);
        float hvA = fmaxf(fminf(ry2, cA.w) - fmaxf(ry1, cA.y), 0.f);
        float inA = wvA * hvA;
        float unA = (aR + aCA) - inA;
        bool supA = (double)inA >= MID * (double)unA;
        float wvB = fmaxf(fminf(rx2, cB.z) - fmaxf(rx1, cB.x), 0.f);
        float hvB = fmaxf(fminf(ry2, cB.w) - fmaxf(ry1, cB.y), 0.f);
        float inB = wvB * hvB;
        float unB = (aR + aCB) - inB;
        bool supB = (double)inB >= MID * (double)unB;
        u64 a = __ballot((int)supA) & cmA;
        u64 b = __ballot((int)supB) & cmB;
        u64 dm = ~((2ull << rr) - 1ull);
        if (rb == cb0) a &= dm;
        if (rb == cb1) b &= dm;
        wA = (lane == rr) ? a : wA;
        wB = (lane == rr) ? b : wB;
    }
    if (r0 + lane < KSEL) {
        if (cb0 >= rb)
            maskT[((size_t)n * MASKW + cb0) * MROWS + r0 + lane] = wA;
        if (cb1 < MASKW)
            maskT[((size_t)n * MASKW + cb1) * MROWS + r0 + lane] = wB;
    }
}

__device__ __forceinline__ u64 bcast64(u64 v, int src) {
    unsigned lo = (unsigned)__builtin_amdgcn_readlane((int)(unsigned)v, src);
    unsigned hi = (unsigned)__builtin_amdgcn_readlane((int)(unsigned)(v >> 32), src);
    return ((u64)hi << 32) | (u64)lo;
}

// Wave64 OR-reduce via DPP, result in lane 63.
__device__ __forceinline__ unsigned or_red_dpp(unsigned v) {
    v |= (unsigned)__builtin_amdgcn_update_dpp(0, (int)v, 0x111, 0xf, 0xf, true);
    v |= (unsigned)__builtin_amdgcn_update_dpp(0, (int)v, 0x112, 0xf, 0xf, true);
    v |= (unsigned)__builtin_amdgcn_update_dpp(0, (int)v, 0x114, 0xf, 0xf, true);
    v |= (unsigned)__builtin_amdgcn_update_dpp(0, (int)v, 0x118, 0xf, 0xf, true);
    v |= (unsigned)__builtin_amdgcn_update_dpp(0, (int)v, 0x142, 0xa, 0xf, false);
    v |= (unsigned)__builtin_amdgcn_update_dpp(0, (int)v, 0x143, 0xc, 0xf, false);
    return v;
}

// Single-wave greedy NMS scan, fully software-pipelined (round-8 design):
//   bulk[16]: word c of rows kept through chunk c-2 (unrolled register gather);
//   nc: word c of ALL rows of chunk c-1 (coalesced), masked by keptbits_{c-1};
//   wc: word c of chunk c's rows (diagonal, coalesced).
// Micro-opt vs round-16: keptbits accumulated UNIFORMLY in registers during
// the chain (the chain is wave-uniform), removing the keep_lds reread + second
// DPP OR-reduce + 2 readlanes from the per-chunk critical path.
__global__ __launch_bounds__(64, 1) void k_scan(const u64* maskT, const int* vcnt,
                                                int* keep, int* nkept) {
    __shared__ int keep_lds[1024];
    int n = blockIdx.x, lane = threadIdx.x;
    int V = vcnt[n];
    const u64* MT = maskT + (size_t)n * MASKW * MROWS;

    for (int i = lane; i < 1024; i += 64) keep_lds[i] = 0;   // single wave: no barrier

    int cnt = 0, cntprev = 0;
    u64 keptprev = 0ull;
    bool full = false;
    int nchunks = (V + 63) >> 6;

    u64 bulk[16];
#pragma unroll
    for (int q = 0; q < 16; ++q) bulk[q] = 0ull;
    u64 wc = MT[lane];      // word 0 of chunk 0 rows
    u64 nc = 0ull;

    for (int c = 0; c < nchunks && !full; ++c) {
        u64 part = 0ull;
#pragma unroll
        for (int q = 0; q < 16; ++q)
            part |= (q * 64 + lane < cntprev) ? bulk[q] : 0ull;
        part |= ((keptprev >> lane) & 1ull) ? nc : 0ull;

        unsigned plo = or_red_dpp((unsigned)part);
        unsigned phi = or_red_dpp((unsigned)(part >> 32));
        u64 cur = ((u64)(unsigned)__builtin_amdgcn_readlane((int)phi, 63) << 32)
                | (u64)(unsigned)__builtin_amdgcn_readlane((int)plo, 63);

        int cntNow = cnt;
        int colN = (c + 1 < NCHUNK) ? (c + 1) : (NCHUNK - 1);
        const u64* colNp = MT + (size_t)colN * MROWS;
        {
            int kr[16];
#pragma unroll
            for (int q = 0; q < 16; ++q) kr[q] = keep_lds[q * 64 + lane];
#pragma unroll
            for (int q = 0; q < 16; ++q) bulk[q] = colNp[kr[q]];
        }
        u64 nc_next = colNp[(size_t)c * 64 + lane];
        u64 wc_next = colNp[(size_t)colN * 64 + lane];

        int base = c * 64;
        int jmax = V - base; if (jmax > 64) jmax = 64;
        u64 avail = ~cur;
        if (jmax < 64) avail &= (1ull << jmax) - 1ull;
        u64 keptbits = 0ull;           // accumulated uniformly (chain is wave-uniform)
        while (avail) {
            int j = __builtin_ctzll(avail);
            if (lane == 0) keep_lds[cnt] = base + j;
            ++cnt;
            keptbits |= 1ull << j;
            if (cnt == POST_K) { full = true; break; }
            u64 wcj = bcast64(wc, j);
            avail &= avail - 1;
            avail &= ~wcj;
        }
        keptprev = keptbits;
        cntprev = cntNow;
        wc = wc_next;
        nc = nc_next;
    }

    for (int i = lane; i < cnt; i += 64) keep[n * POST_K + i] = keep_lds[i];
    if (lane == 0) nkept[n] = cnt;
}

__global__ void k_out(const float4* boxes, const int* keep, const int* nkept, float4* out) {
    int idx = blockIdx.x * blockDim.x + threadIdx.x;
    if (idx >= N_IMGS * POST_K) return;
    int n = idx / POST_K, k = idx - n * POST_K;
    float4 v = make_float4(0.f, 0.f, 0.f, 0.f);
    if (k < nkept[n]) v = boxes[(size_t)n * KSEL + keep[n * POST_K + k]];
    out[idx] = v;
}

extern "C" void kernel_launch(void* const* d_in, const int* in_sizes, int n_in,
                              void* d_out, int out_size, void* d_ws, size_t ws_size,
                              hipStream_t stream) {
    // dict order: obj0, delta0, obj1, delta1, ..., obj4, delta4, anchors
    Ptrs P;
    for (int l = 0; l < 5; ++l) {
        P.obj[l] = (const float*)d_in[2 * l];
        P.del[l] = (const float*)d_in[2 * l + 1];
    }
    P.anch = (const float*)d_in[10];

    // workspace carve
    size_t o = 0;
    auto alloc = [&](size_t bytes) {
        size_t cur = o;
        o = (o + bytes + 255) & ~(size_t)255;
        return cur;
    };
    size_t off_gh     = alloc((size_t)GH_U32 * 4);
    size_t off_cnt    = alloc((size_t)NWS * 4 * 4);   // cntgt, cnteq, basegt, baseeq
    size_t off_nc     = alloc(64 * 4);
    size_t off_piv    = alloc((size_t)N_IMGS * NLVL * 8);
    size_t off_cand   = alloc((size_t)N_IMGS * NLVL * CANDMAX * 8);
    size_t off_sel    = alloc((size_t)N_IMGS * KSEL * 8);
    size_t off_keys2  = alloc((size_t)N_IMGS * MSLOTS * 8);
    size_t off_boxes  = alloc((size_t)N_IMGS * KSEL * 16);
    size_t off_nbox   = alloc((size_t)N_IMGS * KSEL * 16);
    size_t off_mask   = alloc((size_t)N_IMGS * MASKW * MROWS * 8);
    size_t off_vcnt   = alloc(N_IMGS * 4);
    size_t off_keep   = alloc((size_t)N_IMGS * POST_K * 4);
    size_t off_nkept  = alloc(N_IMGS * 4);

    float* out = (float*)d_out;
    if (o > ws_size) {  // workspace too small: emit zeros (visible failure, no crash)
        k_zero_out<<<(out_size + 255) / 256, 256, 0, stream>>>(out, out_size);
        return;
    }

    char* w = (char*)d_ws;
    unsigned* ghist  = (unsigned*)(w + off_gh);
    unsigned* cntgt  = (unsigned*)(w + off_cnt);
    unsigned* cnteq  = cntgt + NWS;
    unsigned* basegt = cntgt + 2 * NWS;
    unsigned* baseeq = cntgt + 3 * NWS;
    int* nc          = (int*)(w + off_nc);
    uint2* pivinfo   = (uint2*)(w + off_piv);
    u64* cand        = (u64*)(w + off_cand);
    uint2* sel       = (uint2*)(w + off_sel);
    u64* keys2       = (u64*)(w + off_keys2);
    float4* boxes    = (float4*)(w + off_boxes);
    float4* nboxes   = (float4*)(w + off_nbox);
    u64* maskT       = (u64*)(w + off_mask);
    int* vcnt        = (int*)(w + off_vcnt);
    int* keep        = (int*)(w + off_keep);
    int* nkept       = (int*)(w + off_nkept);

    k_zero32<<<(GH_U32 + 255) / 256, 256, 0, stream>>>(ghist, GH_U32);
    k_hist<<<N_IMGS * NSLICE, 256, 0, stream>>>(P, ghist);
    k_pivot<<<N_IMGS * NLVL, 1024, 0, stream>>>(ghist, pivinfo, vcnt);
    k_cnt<<<N_IMGS * NSLICE, 256, 0, stream>>>(P, pivinfo, cntgt, cnteq);
    k_off<<<N_IMGS * NLVL, 128, 0, stream>>>(cntgt, cnteq, basegt, baseeq, nc);
    k_write<<<N_IMGS * NSLICE, 256, 0, stream>>>(P, pivinfo, basegt, baseeq, sel, cand);
    k_rank<<<N_IMGS * NLVL, 1024, 0, stream>>>(pivinfo, cand, nc, sel);
    k_sort1<<<N_IMGS * NLVL, 1024, 0, stream>>>(P, sel, keys2);
    k_mergedec<<<(N_IMGS * MSLOTS + 255) / 256, 256, 0, stream>>>(P, keys2, boxes, nboxes, vcnt);
    k_mask<<<dim3(NCHUNK, (MASKW + 1) / 2, N_IMGS), 64, 0, stream>>>(nboxes, maskT);
    k_scan<<<N_IMGS, 64, 0, stream>>>(maskT, vcnt, keep, nkept);
    k_out<<<(N_IMGS * POST_K + 255) / 256, 256, 0, stream>>>((const float4*)boxes, keep, nkept, (float4*)d_out);
}